// Round 15
// baseline (51.413 us; speedup 1.0000x reference)
//
#include <hip/hip_runtime.h>

#define K_SEGS 8192
#define ALPHA_W 0.5f
#define NEG_INF_BITS 0xFF800000
#define WIN 64            // id window per block (chunk spans ~5 ids; 64 = 12x margin)
#define NBLOCKS 2048
#define BLOCK 256
#define NPT 8                             // contiguous nodes per thread
#define SHARD_SZ 32                       // blocks per ticket shard
#define NSHARDS (NBLOCKS / SHARD_SZ)      // 64 shards

// ws layout (unsigned words):
//   [0      .. 8191 ]   seg_sum  (float)
//   [8192   .. 16383]   seg_maxb (unsigned float-bits; init 0 valid since loss >= 0)
//   [16384  .. 24575]   seg_cnt  (unsigned; #blocks touching -> presence)
//   [24576  ..]         shard tickets (one per 64B line), then stage2 ticket
#define SHARD_BASE (3 * K_SEGS)
#define STAGE2_OFF (SHARD_BASE + NSHARDS * 16)
#define WS_WORDS (STAGE2_OFF + 16)

// ---------------------------------------------------------------------------
// Kernel 0: zero accumulators + tickets (ws poisoned 0xAA, never re-poisoned)
// ---------------------------------------------------------------------------
__global__ void init_ws_kernel(unsigned* __restrict__ w) {
    int i = blockIdx.x * blockDim.x + threadIdx.x;
    if (i < WS_WORDS) w[i] = 0u;
}

// ---------------------------------------------------------------------------
// focal loss for one node given its 8 logits + target
// ---------------------------------------------------------------------------
__device__ __forceinline__ float node_focal(float4 a, float4 b, int t) {
    float x0 = a.x, x1 = a.y, x2 = a.z, x3 = a.w;
    float x4 = b.x, x5 = b.y, x6 = b.z, x7 = b.w;
    float m = fmaxf(fmaxf(fmaxf(x0, x1), fmaxf(x2, x3)),
                    fmaxf(fmaxf(x4, x5), fmaxf(x6, x7)));
    float s = __expf(x0 - m) + __expf(x1 - m) + __expf(x2 - m) + __expf(x3 - m)
            + __expf(x4 - m) + __expf(x5 - m) + __expf(x6 - m) + __expf(x7 - m);
    float lse = __logf(s) + m;
    float xt;
    switch (t) {
        case 0: xt = x0; break; case 1: xt = x1; break;
        case 2: xt = x2; break; case 3: xt = x3; break;
        case 4: xt = x4; break; case 5: xt = x5; break;
        case 6: xt = x6; break; default: xt = x7; break;
    }
    float ce = lse - xt;              // >= 0
    float pt = __expf(-ce);           // (0, 1]
    float om = 1.0f - pt;
    return om * om * ce;              // >= 0
}

// ---------------------------------------------------------------------------
// Kernel 1 (fused): PER-THREAD-CONTIGUOUS run accumulation. R13 lesson: the
// per-iteration cross-lane chain (__any + shfl uniformity + 12-op dependent
// butterfly + LDS atomics every 128 nodes) was the invariant cost across
// R11-R13. Now: thread owns 8 contiguous nodes (avg segment=488 -> ~98% of
// threads single-segment), accumulates (rid,rsum,rmax) in registers, flushes
// to the LDS window only on segment change + once at end. ZERO cross-lane
// ops in the hot loop.
// ---------------------------------------------------------------------------
__global__ __launch_bounds__(BLOCK) void node_loss_kernel(
        const float* __restrict__ logits,   // [N, 8]
        const int* __restrict__ targets,    // [N]
        const int* __restrict__ cid,        // [N], sorted
        float* __restrict__ seg_sum,        // [K]
        unsigned* __restrict__ seg_maxb,    // [K]
        unsigned* __restrict__ seg_cnt,     // [K]
        unsigned* __restrict__ shard_tk,    // [NSHARDS*16]
        unsigned* __restrict__ stage2_tk,   // [16]
        float* __restrict__ out,
        int n) {
    __shared__ float lsum[WIN];
    __shared__ int   lmax[WIN];
    __shared__ unsigned s_last;
    __shared__ float s_fa[4], s_fn[4];

    const int tid  = threadIdx.x;
    const int lane = tid & 63;

    const int chunk  = (n + NBLOCKS - 1) / NBLOCKS;   // 1954 for N=4M (even)
    const int cstart = blockIdx.x * chunk;

    if (cstart < n) {
        const int cend = min(cstart + chunk, n);
        const int base = cid[cstart];                 // broadcast load

        for (int j = tid; j < WIN; j += BLOCK) {
            lsum[j] = 0.0f;
            lmax[j] = (int)NEG_INF_BITS;
        }
        __syncthreads();

        const float4* lgf = reinterpret_cast<const float4*>(logits);

        // thread-owned contiguous range [t0, tend)
        const int t0   = cstart + tid * NPT;
        const int tend = min(t0 + NPT, cend);

        // register-held current run
        int   rid  = -1;
        float rsum = 0.0f;
        float rmax = 0.0f;

        // flush helper (expanded inline; rare divergence)
        #define FLUSH_RUN()                                                     \
            if (rid >= 0) {                                                     \
                int off = rid - base;                                           \
                if (off < WIN) {                                                \
                    atomicAdd(&lsum[off], rsum);                                \
                    atomicMax(&lmax[off], __float_as_int(rmax));                \
                } else {  /* pathological window overflow */                    \
                    atomicAdd(&seg_sum[rid], rsum);                             \
                    atomicMax(&seg_maxb[rid], __float_as_uint(rmax));           \
                    atomicAdd(&seg_cnt[rid], 1u);                               \
                }                                                               \
            }

        int i = t0;
        // full 4-node batches: straight-line loads (8 f4 + 2 int2 + 2 int2), no cross-lane
        for (; i + 4 <= tend; i += 4) {
            const float4* p = lgf + (size_t)i * 2;
            float4 x0a = p[0], x0b = p[1];
            float4 x1a = p[2], x1b = p[3];
            float4 x2a = p[4], x2b = p[5];
            float4 x3a = p[6], x3b = p[7];
            int2 tt0 = *reinterpret_cast<const int2*>(targets + i);      // i even
            int2 tt1 = *reinterpret_cast<const int2*>(targets + i + 2);
            int2 cc0 = *reinterpret_cast<const int2*>(cid + i);
            int2 cc1 = *reinterpret_cast<const int2*>(cid + i + 2);

            float L0 = node_focal(x0a, x0b, tt0.x);
            float L1 = node_focal(x1a, x1b, tt0.y);
            float L2 = node_focal(x2a, x2b, tt1.x);
            float L3 = node_focal(x3a, x3b, tt1.y);

            // run accumulation (boundary ~once per 488 nodes -> rare divergence)
            if (cc0.x != rid) { FLUSH_RUN(); rid = cc0.x; rsum = 0.0f; rmax = 0.0f; }
            rsum += L0; rmax = fmaxf(rmax, L0);
            if (cc0.y != rid) { FLUSH_RUN(); rid = cc0.y; rsum = 0.0f; rmax = 0.0f; }
            rsum += L1; rmax = fmaxf(rmax, L1);
            if (cc1.x != rid) { FLUSH_RUN(); rid = cc1.x; rsum = 0.0f; rmax = 0.0f; }
            rsum += L2; rmax = fmaxf(rmax, L2);
            if (cc1.y != rid) { FLUSH_RUN(); rid = cc1.y; rsum = 0.0f; rmax = 0.0f; }
            rsum += L3; rmax = fmaxf(rmax, L3);
        }
        // scalar tail (0..3 nodes)
        for (; i < tend; ++i) {
            const float4* p = lgf + (size_t)i * 2;
            float L = node_focal(p[0], p[1], targets[i]);
            int c = cid[i];
            if (c != rid) { FLUSH_RUN(); rid = c; rsum = 0.0f; rmax = 0.0f; }
            rsum += L; rmax = fmaxf(rmax, L);
        }
        FLUSH_RUN();
        #undef FLUSH_RUN

        __syncthreads();

        // flush touched window entries: ~5-10 global atomic triples per block
        for (int j = tid; j < WIN; j += BLOCK) {
            int mb = lmax[j];
            if (mb != (int)NEG_INF_BITS) {
                atomicAdd(&seg_sum[base + j], lsum[j]);
                atomicMax(&seg_maxb[base + j], (unsigned)mb);  // mb >= 0 bits
                atomicAdd(&seg_cnt[base + j], 1u);
            }
        }
    }

    // ---- sharded ticket: last finished block overall runs the finalize ----
    asm volatile("s_waitcnt vmcnt(0)" ::: "memory");  // own flush atomics acked
    __syncthreads();                                  // whole block drained
    if (tid == 0) {
        unsigned fin = 0u;
        unsigned my = atomicAdd(&shard_tk[(blockIdx.x / SHARD_SZ) * 16], 1u);
        if (my == (unsigned)(SHARD_SZ - 1)) {
            fin = atomicAdd(&stage2_tk[0], 1u) + 1u;
        }
        s_last = (fin == (unsigned)NSHARDS) ? 1u : 0u;
    }
    __syncthreads();
    if (s_last) {
        float acc = 0.0f, np = 0.0f;
        // Pipelined: unconditional agent-scope loads, unrolled -> many in flight
        #pragma unroll 8
        for (int k = tid; k < K_SEGS; k += BLOCK) {
            unsigned c = __hip_atomic_load(&seg_cnt[k],  __ATOMIC_RELAXED, __HIP_MEMORY_SCOPE_AGENT);
            float s    = __hip_atomic_load(&seg_sum[k],  __ATOMIC_RELAXED, __HIP_MEMORY_SCOPE_AGENT);
            unsigned m = __hip_atomic_load(&seg_maxb[k], __ATOMIC_RELAXED, __HIP_MEMORY_SCOPE_AGENT);
            if (c != 0u) {
                acc += ALPHA_W * s + (1.0f - ALPHA_W) * __uint_as_float(m);
                np += 1.0f;
            }
        }
        #pragma unroll
        for (int o = 32; o > 0; o >>= 1) {
            acc += __shfl_xor(acc, o);
            np  += __shfl_xor(np, o);
        }
        if (lane == 0) { s_fa[tid >> 6] = acc; s_fn[tid >> 6] = np; }
        __syncthreads();
        if (tid == 0) {
            float a = s_fa[0] + s_fa[1] + s_fa[2] + s_fa[3];
            float c = s_fn[0] + s_fn[1] + s_fn[2] + s_fn[3];
            out[0] = a / fmaxf(c, 1.0f);
        }
    }
}

// ---------------------------------------------------------------------------
extern "C" void kernel_launch(void* const* d_in, const int* in_sizes, int n_in,
                              void* d_out, int out_size, void* d_ws, size_t ws_size,
                              hipStream_t stream) {
    const float* logits = (const float*)d_in[0];
    const int* targets  = (const int*)d_in[1];
    const int* cid      = (const int*)d_in[2];
    float* out          = (float*)d_out;

    const int n = in_sizes[1];   // N = 4,000,000

    unsigned* w        = (unsigned*)d_ws;
    float* seg_sum     = (float*)w;
    unsigned* seg_maxb = w + K_SEGS;
    unsigned* seg_cnt  = w + 2 * K_SEGS;
    unsigned* shard_tk = w + SHARD_BASE;
    unsigned* stage2_tk= w + STAGE2_OFF;

    init_ws_kernel<<<(WS_WORDS + 255) / 256, 256, 0, stream>>>(w);

    node_loss_kernel<<<NBLOCKS, BLOCK, 0, stream>>>(logits, targets, cid,
                                                    seg_sum, seg_maxb, seg_cnt,
                                                    shard_tk, stage2_tk, out, n);
}

// Round 18
// 40.998 us; speedup vs baseline: 1.2540x; 1.2540x over previous
//
#include <hip/hip_runtime.h>

#define K_SEGS 8192
#define ALPHA_W 0.5f
#define NEG_INF_BITS 0xFF800000
#define WIN 64            // id window per block (chunk spans ~5 ids; 64 = 12x margin)
#define NBLOCKS 2048
#define BLOCK 256
#define SHARD_SZ 32                       // blocks per ticket shard
#define NSHARDS (NBLOCKS / SHARD_SZ)      // 64 shards

// ws layout (unsigned words):
//   [0      .. 8191 ]   seg_sum  (float)
//   [8192   .. 16383]   seg_maxb (unsigned float-bits; init 0 valid since loss >= 0)
//   [16384  .. 24575]   seg_cnt  (unsigned; #blocks touching -> presence)
//   [24576  ..]         shard tickets (one per 64B line), then stage2 ticket
#define SHARD_BASE (3 * K_SEGS)
#define STAGE2_OFF (SHARD_BASE + NSHARDS * 16)
#define WS_WORDS (STAGE2_OFF + 16)

// ---------------------------------------------------------------------------
// Kernel 0: zero accumulators + tickets (ws poisoned 0xAA, never re-poisoned)
// ---------------------------------------------------------------------------
__global__ void init_ws_kernel(unsigned* __restrict__ w) {
    int i = blockIdx.x * blockDim.x + threadIdx.x;
    if (i < WS_WORDS) w[i] = 0u;
}

// ---------------------------------------------------------------------------
// focal loss for one node given its 8 logits + target
// ---------------------------------------------------------------------------
__device__ __forceinline__ float node_focal(float4 a, float4 b, int t) {
    float x0 = a.x, x1 = a.y, x2 = a.z, x3 = a.w;
    float x4 = b.x, x5 = b.y, x6 = b.z, x7 = b.w;
    float m = fmaxf(fmaxf(fmaxf(x0, x1), fmaxf(x2, x3)),
                    fmaxf(fmaxf(x4, x5), fmaxf(x6, x7)));
    float s = __expf(x0 - m) + __expf(x1 - m) + __expf(x2 - m) + __expf(x3 - m)
            + __expf(x4 - m) + __expf(x5 - m) + __expf(x6 - m) + __expf(x7 - m);
    float lse = __logf(s) + m;
    float xt;
    switch (t) {
        case 0: xt = x0; break; case 1: xt = x1; break;
        case 2: xt = x2; break; case 3: xt = x3; break;
        case 4: xt = x4; break; case 5: xt = x5; break;
        case 6: xt = x6; break; default: xt = x7; break;
    }
    float ce = lse - xt;              // >= 0
    float pt = __expf(-ce);           // (0, 1]
    float om = 1.0f - pt;
    return om * om * ce;              // >= 0
}

// per-thread batch: 2 consecutive nodes, wave-contiguous across lanes
struct Batch {
    float4 a0, a1, b0, b1;
    int ta, tb, ca, cb;
    bool v;
};

__device__ __forceinline__ Batch load_batch(const float4* __restrict__ lgf,
                                            const int* __restrict__ targets,
                                            const int* __restrict__ cid,
                                            int i0, int cend) {
    Batch b;
    b.v = (i0 < cend);               // pairs intact (chunk even, i0 even)
    if (b.v) {
        const float4* p = lgf + (size_t)i0 * 2;
        b.a0 = p[0]; b.a1 = p[1]; b.b0 = p[2]; b.b1 = p[3];
        int2 tt = *reinterpret_cast<const int2*>(targets + i0);
        int2 cc = *reinterpret_cast<const int2*>(cid + i0);
        b.ta = tt.x; b.tb = tt.y; b.ca = cc.x; b.cb = cc.y;
    } else {
        b.a0 = b.a1 = b.b0 = b.b1 = make_float4(0.f, 0.f, 0.f, 0.f);
        b.ta = b.tb = 0; b.ca = -1; b.cb = -2;   // mismatching sentinels
    }
    return b;
}

// ---------------------------------------------------------------------------
// Kernel 1 (fused): R11 wave-contiguous structure + 2-WAY UNROLLED PASSES.
// R15 lesson: per-thread-contiguous (256B lane stride) broke coalescing (-9us).
// R13 lesson: conditional prefetch never materialized (VGPR stayed 32).
// Here: both half-pass batches (12 independent VMEM ops) are loaded
// unconditionally at pass start at wave-contiguous addresses, and the two
// independent butterfly chains interleave. Ticket/finalize proven in R10/R11.
// ---------------------------------------------------------------------------
__global__ __launch_bounds__(BLOCK) void node_loss_kernel(
        const float* __restrict__ logits,   // [N, 8]
        const int* __restrict__ targets,    // [N]
        const int* __restrict__ cid,        // [N], sorted
        float* __restrict__ seg_sum,        // [K]
        unsigned* __restrict__ seg_maxb,    // [K]
        unsigned* __restrict__ seg_cnt,     // [K]
        unsigned* __restrict__ shard_tk,    // [NSHARDS*16]
        unsigned* __restrict__ stage2_tk,   // [16]
        float* __restrict__ out,
        int n) {
    __shared__ float lsum[WIN];
    __shared__ int   lmax[WIN];
    __shared__ unsigned s_last;
    __shared__ float s_fa[4], s_fn[4];

    const int tid  = threadIdx.x;
    const int lane = tid & 63;

    const int chunk  = (n + NBLOCKS - 1) / NBLOCKS;   // 1954 for N=4M (even)
    const int cstart = blockIdx.x * chunk;

    if (cstart < n) {
        const int cend = min(cstart + chunk, n);
        const int base = cid[cstart];                 // broadcast load

        for (int j = tid; j < WIN; j += BLOCK) {
            lsum[j] = 0.0f;
            lmax[j] = (int)NEG_INF_BITS;
        }
        __syncthreads();

        const float4* lgf = reinterpret_cast<const float4*>(logits);
        const int span = BLOCK * 2;                   // 512 nodes per half-pass

        for (int p0 = cstart; p0 < cend; p0 += 2 * span) {
            // ---- issue BOTH half-pass load clusters up-front (12 VMEM ops) ----
            Batch A = load_batch(lgf, targets, cid, p0 + tid * 2, cend);
            Batch B = load_batch(lgf, targets, cid, p0 + span + tid * 2, cend);

            // ---- compute (independent chains) ----
            float laA = 0.f, lbA = 0.f, laB = 0.f, lbB = 0.f;
            int offaA = -1, offbA = -2, offaB = -1, offbB = -2;
            if (A.v) {
                laA = node_focal(A.a0, A.a1, A.ta);
                lbA = node_focal(A.b0, A.b1, A.tb);
                offaA = A.ca - base; offbA = A.cb - base;
            }
            if (B.v) {
                laB = node_focal(B.a0, B.a1, B.ta);
                lbB = node_focal(B.b0, B.b1, B.tb);
                offaB = B.ca - base; offbB = B.cb - base;
            }

            const int uA = __shfl(offaA, 0);
            const int uB = __shfl(offaB, 0);
            const bool unifA = __all(offaA == uA && offbA == uA) && (uA < WIN);
            const bool unifB = __all(offaB == uB && offbB == uB) && (uB < WIN);

            // ---- two independent butterflies, interleaved by the scheduler ----
            float tsA = laA + lbA, tmA = fmaxf(laA, lbA);
            float tsB = laB + lbB, tmB = fmaxf(laB, lbB);
            #pragma unroll
            for (int o = 32; o > 0; o >>= 1) {
                tsA += __shfl_xor(tsA, o);
                tsB += __shfl_xor(tsB, o);
                tmA = fmaxf(tmA, __shfl_xor(tmA, o));
                tmB = fmaxf(tmB, __shfl_xor(tmB, o));
            }

            if (unifA) {
                if (lane == 0) {
                    atomicAdd(&lsum[uA], tsA);
                    atomicMax(&lmax[uA], __float_as_int(tmA));
                }
            } else if (A.v) {
                if (offaA < WIN) {
                    atomicAdd(&lsum[offaA], laA);
                    atomicMax(&lmax[offaA], __float_as_int(laA));
                } else {  // pathological overflow: global accumulate
                    atomicAdd(&seg_sum[base + offaA], laA);
                    atomicMax(&seg_maxb[base + offaA], __float_as_uint(laA));
                    atomicAdd(&seg_cnt[base + offaA], 1u);
                }
                if (offbA < WIN) {
                    atomicAdd(&lsum[offbA], lbA);
                    atomicMax(&lmax[offbA], __float_as_int(lbA));
                } else {
                    atomicAdd(&seg_sum[base + offbA], lbA);
                    atomicMax(&seg_maxb[base + offbA], __float_as_uint(lbA));
                    atomicAdd(&seg_cnt[base + offbA], 1u);
                }
            }

            if (unifB) {
                if (lane == 0) {
                    atomicAdd(&lsum[uB], tsB);
                    atomicMax(&lmax[uB], __float_as_int(tmB));
                }
            } else if (B.v) {
                if (offaB < WIN) {
                    atomicAdd(&lsum[offaB], laB);
                    atomicMax(&lmax[offaB], __float_as_int(laB));
                } else {
                    atomicAdd(&seg_sum[base + offaB], laB);
                    atomicMax(&seg_maxb[base + offaB], __float_as_uint(laB));
                    atomicAdd(&seg_cnt[base + offaB], 1u);
                }
                if (offbB < WIN) {
                    atomicAdd(&lsum[offbB], lbB);
                    atomicMax(&lmax[offbB], __float_as_int(lbB));
                } else {
                    atomicAdd(&seg_sum[base + offbB], lbB);
                    atomicMax(&seg_maxb[base + offbB], __float_as_uint(lbB));
                    atomicAdd(&seg_cnt[base + offbB], 1u);
                }
            }
        }
        __syncthreads();

        // flush touched window entries: ~5-10 global atomic triples per block
        for (int j = tid; j < WIN; j += BLOCK) {
            int mb = lmax[j];
            if (mb != (int)NEG_INF_BITS) {
                atomicAdd(&seg_sum[base + j], lsum[j]);
                atomicMax(&seg_maxb[base + j], (unsigned)mb);  // mb >= 0 bits
                atomicAdd(&seg_cnt[base + j], 1u);
            }
        }
    }

    // ---- sharded ticket: last finished block overall runs the finalize ----
    asm volatile("s_waitcnt vmcnt(0)" ::: "memory");  // own flush atomics acked
    __syncthreads();                                  // whole block drained
    if (tid == 0) {
        unsigned fin = 0u;
        unsigned my = atomicAdd(&shard_tk[(blockIdx.x / SHARD_SZ) * 16], 1u);
        if (my == (unsigned)(SHARD_SZ - 1)) {
            fin = atomicAdd(&stage2_tk[0], 1u) + 1u;
        }
        s_last = (fin == (unsigned)NSHARDS) ? 1u : 0u;
    }
    __syncthreads();
    if (s_last) {
        float acc = 0.0f, np = 0.0f;
        // Pipelined: unconditional agent-scope loads, unrolled -> many in flight
        #pragma unroll 8
        for (int k = tid; k < K_SEGS; k += BLOCK) {
            unsigned c = __hip_atomic_load(&seg_cnt[k],  __ATOMIC_RELAXED, __HIP_MEMORY_SCOPE_AGENT);
            float s    = __hip_atomic_load(&seg_sum[k],  __ATOMIC_RELAXED, __HIP_MEMORY_SCOPE_AGENT);
            unsigned m = __hip_atomic_load(&seg_maxb[k], __ATOMIC_RELAXED, __HIP_MEMORY_SCOPE_AGENT);
            if (c != 0u) {
                acc += ALPHA_W * s + (1.0f - ALPHA_W) * __uint_as_float(m);
                np += 1.0f;
            }
        }
        #pragma unroll
        for (int o = 32; o > 0; o >>= 1) {
            acc += __shfl_xor(acc, o);
            np  += __shfl_xor(np, o);
        }
        if (lane == 0) { s_fa[tid >> 6] = acc; s_fn[tid >> 6] = np; }
        __syncthreads();
        if (tid == 0) {
            float a = s_fa[0] + s_fa[1] + s_fa[2] + s_fa[3];
            float c = s_fn[0] + s_fn[1] + s_fn[2] + s_fn[3];
            out[0] = a / fmaxf(c, 1.0f);
        }
    }
}

// ---------------------------------------------------------------------------
extern "C" void kernel_launch(void* const* d_in, const int* in_sizes, int n_in,
                              void* d_out, int out_size, void* d_ws, size_t ws_size,
                              hipStream_t stream) {
    const float* logits = (const float*)d_in[0];
    const int* targets  = (const int*)d_in[1];
    const int* cid      = (const int*)d_in[2];
    float* out          = (float*)d_out;

    const int n = in_sizes[1];   // N = 4,000,000

    unsigned* w        = (unsigned*)d_ws;
    float* seg_sum     = (float*)w;
    unsigned* seg_maxb = w + K_SEGS;
    unsigned* seg_cnt  = w + 2 * K_SEGS;
    unsigned* shard_tk = w + SHARD_BASE;
    unsigned* stage2_tk= w + STAGE2_OFF;

    init_ws_kernel<<<(WS_WORDS + 255) / 256, 256, 0, stream>>>(w);

    node_loss_kernel<<<NBLOCKS, BLOCK, 0, stream>>>(logits, targets, cid,
                                                    seg_sum, seg_maxb, seg_cnt,
                                                    shard_tk, stage2_tk, out, n);
}

// Round 19
// 40.165 us; speedup vs baseline: 1.2800x; 1.0207x over previous
//
#include <hip/hip_runtime.h>

#define K_SEGS 8192
#define ALPHA_W 0.5f
#define NEG_INF_BITS 0xFF800000
#define WIN 64            // id window per block (chunk spans ~5 ids; 64 = 12x margin)
#define NBLOCKS 2048
#define BLOCK 256
#define SHARD_SZ 32                       // blocks per ticket shard
#define NSHARDS (NBLOCKS / SHARD_SZ)      // 64 shards

// ws layout (unsigned words):
//   [0      .. 8191 ]   seg_sum  (float)
//   [8192   .. 16383]   seg_maxb (unsigned float-bits; init 0 valid since loss >= 0)
//   [16384  .. 24575]   seg_cnt  (unsigned; #blocks touching -> presence)
//   [24576  ..]         shard tickets (one per 64B line), then stage2 ticket
#define SHARD_BASE (3 * K_SEGS)
#define STAGE2_OFF (SHARD_BASE + NSHARDS * 16)
#define WS_WORDS (STAGE2_OFF + 16)

// ---------------------------------------------------------------------------
// Kernel 0: zero accumulators + tickets (ws poisoned 0xAA, never re-poisoned)
// ---------------------------------------------------------------------------
__global__ void init_ws_kernel(unsigned* __restrict__ w) {
    int i = blockIdx.x * blockDim.x + threadIdx.x;
    if (i < WS_WORDS) w[i] = 0u;
}

// ---------------------------------------------------------------------------
// focal loss for one node given its 8 logits + target
// ---------------------------------------------------------------------------
__device__ __forceinline__ float node_focal(float4 a, float4 b, int t) {
    float x0 = a.x, x1 = a.y, x2 = a.z, x3 = a.w;
    float x4 = b.x, x5 = b.y, x6 = b.z, x7 = b.w;
    float m = fmaxf(fmaxf(fmaxf(x0, x1), fmaxf(x2, x3)),
                    fmaxf(fmaxf(x4, x5), fmaxf(x6, x7)));
    float s = __expf(x0 - m) + __expf(x1 - m) + __expf(x2 - m) + __expf(x3 - m)
            + __expf(x4 - m) + __expf(x5 - m) + __expf(x6 - m) + __expf(x7 - m);
    float lse = __logf(s) + m;
    float xt;
    switch (t) {
        case 0: xt = x0; break; case 1: xt = x1; break;
        case 2: xt = x2; break; case 3: xt = x3; break;
        case 4: xt = x4; break; case 5: xt = x5; break;
        case 6: xt = x6; break; default: xt = x7; break;
    }
    float ce = lse - xt;              // >= 0
    float pt = __expf(-ce);           // (0, 1]
    float om = 1.0f - pt;
    return om * om * ce;              // >= 0
}

// per-thread batch: 2 consecutive nodes, wave-contiguous across lanes.
// UNCONDITIONAL loads via clamped index (every block has >= 2 nodes, even).
struct Batch {
    float4 a0, a1, b0, b1;
    int ta, tb, ca, cb;
    bool v;
};

__device__ __forceinline__ Batch load_batch(const float4* __restrict__ lgf,
                                            const int* __restrict__ targets,
                                            const int* __restrict__ cid,
                                            int i0, int cend) {
    Batch b;
    b.v = (i0 < cend);
    const int ic = min(i0, cend - 2);        // always valid, even
    const float4* p = lgf + (size_t)ic * 2;
    b.a0 = p[0]; b.a1 = p[1]; b.b0 = p[2]; b.b1 = p[3];   // unconditional
    int2 tt = *reinterpret_cast<const int2*>(targets + ic);
    int2 cc = *reinterpret_cast<const int2*>(cid + ic);
    b.ta = tt.x; b.tb = tt.y;
    b.ca = b.v ? cc.x : -1;                  // mask RESULT, not load
    b.cb = b.v ? cc.y : -2;
    return b;
}

// ---------------------------------------------------------------------------
// Kernel 1 (fused): R11 wave-contiguous structure + 2-way unrolled passes with
// CLAMPED UNCONDITIONAL loads. R13/R16 lesson: guarded loads get sunk by the
// compiler (VGPR stuck at 32 -> zero MLP); clamp-and-mask forces the 12 VMEM
// ops to issue up-front. Manipulation check: VGPR must rise to >= 64.
// ---------------------------------------------------------------------------
__global__ __launch_bounds__(BLOCK) void node_loss_kernel(
        const float* __restrict__ logits,   // [N, 8]
        const int* __restrict__ targets,    // [N]
        const int* __restrict__ cid,        // [N], sorted
        float* __restrict__ seg_sum,        // [K]
        unsigned* __restrict__ seg_maxb,    // [K]
        unsigned* __restrict__ seg_cnt,     // [K]
        unsigned* __restrict__ shard_tk,    // [NSHARDS*16]
        unsigned* __restrict__ stage2_tk,   // [16]
        float* __restrict__ out,
        int n) {
    __shared__ float lsum[WIN];
    __shared__ int   lmax[WIN];
    __shared__ unsigned s_last;
    __shared__ float s_fa[4], s_fn[4];

    const int tid  = threadIdx.x;
    const int lane = tid & 63;

    const int chunk  = (n + NBLOCKS - 1) / NBLOCKS;   // 1954 for N=4M (even)
    const int cstart = blockIdx.x * chunk;

    if (cstart < n) {
        const int cend = min(cstart + chunk, n);
        const int base = cid[cstart];                 // broadcast load

        for (int j = tid; j < WIN; j += BLOCK) {
            lsum[j] = 0.0f;
            lmax[j] = (int)NEG_INF_BITS;
        }
        __syncthreads();

        const float4* lgf = reinterpret_cast<const float4*>(logits);
        const int span = BLOCK * 2;                   // 512 nodes per half-pass

        for (int p0 = cstart; p0 < cend; p0 += 2 * span) {
            // ---- BOTH half-pass load clusters, unconditional (12 VMEM ops) ----
            Batch A = load_batch(lgf, targets, cid, p0 + tid * 2, cend);
            Batch B = load_batch(lgf, targets, cid, p0 + span + tid * 2, cend);

            // ---- compute unconditionally (clamped data is finite), mask after ----
            float laA = node_focal(A.a0, A.a1, A.ta);
            float lbA = node_focal(A.b0, A.b1, A.tb);
            float laB = node_focal(B.a0, B.a1, B.ta);
            float lbB = node_focal(B.b0, B.b1, B.tb);
            laA = A.v ? laA : 0.0f;  lbA = A.v ? lbA : 0.0f;
            laB = B.v ? laB : 0.0f;  lbB = B.v ? lbB : 0.0f;
            const int offaA = A.v ? (A.ca - base) : -1;
            const int offbA = A.v ? (A.cb - base) : -2;
            const int offaB = B.v ? (B.ca - base) : -1;
            const int offbB = B.v ? (B.cb - base) : -2;

            const int uA = __shfl(offaA, 0);
            const int uB = __shfl(offaB, 0);
            const bool unifA = __all(offaA == uA && offbA == uA) && (uA < WIN);
            const bool unifB = __all(offaB == uB && offbB == uB) && (uB < WIN);

            // ---- two independent butterflies, interleaved by the scheduler ----
            float tsA = laA + lbA, tmA = fmaxf(laA, lbA);
            float tsB = laB + lbB, tmB = fmaxf(laB, lbB);
            #pragma unroll
            for (int o = 32; o > 0; o >>= 1) {
                tsA += __shfl_xor(tsA, o);
                tsB += __shfl_xor(tsB, o);
                tmA = fmaxf(tmA, __shfl_xor(tmA, o));
                tmB = fmaxf(tmB, __shfl_xor(tmB, o));
            }

            if (unifA) {
                if (lane == 0) {
                    atomicAdd(&lsum[uA], tsA);
                    atomicMax(&lmax[uA], __float_as_int(tmA));
                }
            } else if (A.v) {
                if (offaA < WIN) {
                    atomicAdd(&lsum[offaA], laA);
                    atomicMax(&lmax[offaA], __float_as_int(laA));
                } else {  // pathological overflow: global accumulate
                    atomicAdd(&seg_sum[base + offaA], laA);
                    atomicMax(&seg_maxb[base + offaA], __float_as_uint(laA));
                    atomicAdd(&seg_cnt[base + offaA], 1u);
                }
                if (offbA < WIN) {
                    atomicAdd(&lsum[offbA], lbA);
                    atomicMax(&lmax[offbA], __float_as_int(lbA));
                } else {
                    atomicAdd(&seg_sum[base + offbA], lbA);
                    atomicMax(&seg_maxb[base + offbA], __float_as_uint(lbA));
                    atomicAdd(&seg_cnt[base + offbA], 1u);
                }
            }

            if (unifB) {
                if (lane == 0) {
                    atomicAdd(&lsum[uB], tsB);
                    atomicMax(&lmax[uB], __float_as_int(tmB));
                }
            } else if (B.v) {
                if (offaB < WIN) {
                    atomicAdd(&lsum[offaB], laB);
                    atomicMax(&lmax[offaB], __float_as_int(laB));
                } else {
                    atomicAdd(&seg_sum[base + offaB], laB);
                    atomicMax(&seg_maxb[base + offaB], __float_as_uint(laB));
                    atomicAdd(&seg_cnt[base + offaB], 1u);
                }
                if (offbB < WIN) {
                    atomicAdd(&lsum[offbB], lbB);
                    atomicMax(&lmax[offbB], __float_as_int(lbB));
                } else {
                    atomicAdd(&seg_sum[base + offbB], lbB);
                    atomicMax(&seg_maxb[base + offbB], __float_as_uint(lbB));
                    atomicAdd(&seg_cnt[base + offbB], 1u);
                }
            }
        }
        __syncthreads();

        // flush touched window entries: ~5-10 global atomic triples per block
        for (int j = tid; j < WIN; j += BLOCK) {
            int mb = lmax[j];
            if (mb != (int)NEG_INF_BITS) {
                atomicAdd(&seg_sum[base + j], lsum[j]);
                atomicMax(&seg_maxb[base + j], (unsigned)mb);  // mb >= 0 bits
                atomicAdd(&seg_cnt[base + j], 1u);
            }
        }
    }

    // ---- sharded ticket: last finished block overall runs the finalize ----
    asm volatile("s_waitcnt vmcnt(0)" ::: "memory");  // own flush atomics acked
    __syncthreads();                                  // whole block drained
    if (tid == 0) {
        unsigned fin = 0u;
        unsigned my = atomicAdd(&shard_tk[(blockIdx.x / SHARD_SZ) * 16], 1u);
        if (my == (unsigned)(SHARD_SZ - 1)) {
            fin = atomicAdd(&stage2_tk[0], 1u) + 1u;
        }
        s_last = (fin == (unsigned)NSHARDS) ? 1u : 0u;
    }
    __syncthreads();
    if (s_last) {
        float acc = 0.0f, np = 0.0f;
        // Pipelined: unconditional agent-scope loads, unrolled -> many in flight
        #pragma unroll 8
        for (int k = tid; k < K_SEGS; k += BLOCK) {
            unsigned c = __hip_atomic_load(&seg_cnt[k],  __ATOMIC_RELAXED, __HIP_MEMORY_SCOPE_AGENT);
            float s    = __hip_atomic_load(&seg_sum[k],  __ATOMIC_RELAXED, __HIP_MEMORY_SCOPE_AGENT);
            unsigned m = __hip_atomic_load(&seg_maxb[k], __ATOMIC_RELAXED, __HIP_MEMORY_SCOPE_AGENT);
            if (c != 0u) {
                acc += ALPHA_W * s + (1.0f - ALPHA_W) * __uint_as_float(m);
                np += 1.0f;
            }
        }
        #pragma unroll
        for (int o = 32; o > 0; o >>= 1) {
            acc += __shfl_xor(acc, o);
            np  += __shfl_xor(np, o);
        }
        if (lane == 0) { s_fa[tid >> 6] = acc; s_fn[tid >> 6] = np; }
        __syncthreads();
        if (tid == 0) {
            float a = s_fa[0] + s_fa[1] + s_fa[2] + s_fa[3];
            float c = s_fn[0] + s_fn[1] + s_fn[2] + s_fn[3];
            out[0] = a / fmaxf(c, 1.0f);
        }
    }
}

// ---------------------------------------------------------------------------
extern "C" void kernel_launch(void* const* d_in, const int* in_sizes, int n_in,
                              void* d_out, int out_size, void* d_ws, size_t ws_size,
                              hipStream_t stream) {
    const float* logits = (const float*)d_in[0];
    const int* targets  = (const int*)d_in[1];
    const int* cid      = (const int*)d_in[2];
    float* out          = (float*)d_out;

    const int n = in_sizes[1];   // N = 4,000,000

    unsigned* w        = (unsigned*)d_ws;
    float* seg_sum     = (float*)w;
    unsigned* seg_maxb = w + K_SEGS;
    unsigned* seg_cnt  = w + 2 * K_SEGS;
    unsigned* shard_tk = w + SHARD_BASE;
    unsigned* stage2_tk= w + STAGE2_OFF;

    init_ws_kernel<<<(WS_WORDS + 255) / 256, 256, 0, stream>>>(w);

    node_loss_kernel<<<NBLOCKS, BLOCK, 0, stream>>>(logits, targets, cid,
                                                    seg_sum, seg_maxb, seg_cnt,
                                                    shard_tk, stage2_tk, out, n);
}